// Round 11
// baseline (520.207 us; speedup 1.0000x reference)
//
#include <hip/hip_runtime.h>
#include <math.h>

#define BB 64
#define II 1024
#define HH 1024
#define MM 1024
#define GH (BB * HH)   // 65536 elements per gate plane

// Clang-native 4-float vector: required by __builtin_nontemporal_load/store
// (HIP's float4 is a HIP_vector_type class, which the builtin rejects).
typedef float f32x4 __attribute__((ext_vector_type(4)));

// ---------------------------------------------------------------------------
// Kernel 1: the six input projections.
//   gates[w][b][h], w in {0:q, 1:k(scaled), 2:v, 3:i(sig), 4:f(sig), 5:o(sig)}
// Design: lane = batch row (B==64==wave), each wave owns 3 output columns.
//   W-row addresses are wave-uniform -> scalar loads; x rows stream via L1
//   (64 rows x 4KB working set re-read per wave, L1/L2 resident).
//   256 blocks x 8 waves x 3 cols = 6144 = 6*1024 columns.
// ---------------------------------------------------------------------------
__global__ __launch_bounds__(512) void gates_kernel(
    const float* __restrict__ x,
    const float* __restrict__ Wq, const float* __restrict__ bq,
    const float* __restrict__ Wk, const float* __restrict__ bk,
    const float* __restrict__ Wv, const float* __restrict__ bv,
    const float* __restrict__ Wi, const float* __restrict__ bi,
    const float* __restrict__ Wf, const float* __restrict__ bf,
    const float* __restrict__ Wo, const float* __restrict__ bo,
    float* __restrict__ gates)
{
    const int lane = threadIdx.x & 63;
    const int wv   = __builtin_amdgcn_readfirstlane((int)(threadIdx.x >> 6));
    const int g0   = blockIdx.x * 24 + wv * 3;

    const float* wrow[3];
    float        bias[3];
    #pragma unroll
    for (int j = 0; j < 3; ++j) {
        const int g = g0 + j;
        const int s = g >> 10;        // which weight
        const int h = g & 1023;
        const float* Wb; const float* bb;
        switch (s) {
            case 0:  Wb = Wq; bb = bq; break;
            case 1:  Wb = Wk; bb = bk; break;
            case 2:  Wb = Wv; bb = bv; break;
            case 3:  Wb = Wi; bb = bi; break;
            case 4:  Wb = Wf; bb = bf; break;
            default: Wb = Wo; bb = bo; break;
        }
        wrow[j] = Wb + (size_t)h * II;
        bias[j] = bb[h];
    }

    const float* xrow = x + (size_t)lane * II;

    float a0 = 0.f, a1 = 0.f, a2 = 0.f;
    #pragma unroll 2
    for (int k = 0; k < II; k += 4) {
        const f32x4 xv = *reinterpret_cast<const f32x4*>(&xrow[k]);
        const f32x4 w0 = *reinterpret_cast<const f32x4*>(&wrow[0][k]);
        const f32x4 w1 = *reinterpret_cast<const f32x4*>(&wrow[1][k]);
        const f32x4 w2 = *reinterpret_cast<const f32x4*>(&wrow[2][k]);
        a0 += xv.x * w0.x + xv.y * w0.y + xv.z * w0.z + xv.w * w0.w;
        a1 += xv.x * w1.x + xv.y * w1.y + xv.z * w1.z + xv.w * w1.w;
        a2 += xv.x * w2.x + xv.y * w2.y + xv.z * w2.z + xv.w * w2.w;
    }

    float accs[3] = {a0, a1, a2};
    #pragma unroll
    for (int j = 0; j < 3; ++j) {
        const int g = g0 + j;
        const int s = g >> 10;
        const int h = g & 1023;
        float r = accs[j] + bias[j];
        if (s == 1)      r *= 0.03125f;                    // 1/sqrt(1024)
        else if (s >= 3) r = 1.0f / (1.0f + expf(-r));     // sigmoid
        gates[(size_t)s * GH + (size_t)lane * HH + h] = r;
    }
}

// ---------------------------------------------------------------------------
// Kernel 2: n = f*n_prev + i*k ; denom[b] = max(|dot(n, q)|, 1)
// One block per batch row.
// ---------------------------------------------------------------------------
__global__ __launch_bounds__(256) void n_denom_kernel(
    const float* __restrict__ gates, const float* __restrict__ n_prev,
    float* __restrict__ n_out, float* __restrict__ denom)
{
    const int b   = blockIdx.x;
    const int tid = threadIdx.x;
    const int idx = tid << 2;

    const float* qrow = gates + 0 * GH + (size_t)b * HH;
    const float* krow = gates + 1 * GH + (size_t)b * HH;
    const float* irow = gates + 3 * GH + (size_t)b * HH;
    const float* frow = gates + 4 * GH + (size_t)b * HH;

    const f32x4 f4  = *reinterpret_cast<const f32x4*>(&frow[idx]);
    const f32x4 i4  = *reinterpret_cast<const f32x4*>(&irow[idx]);
    const f32x4 k4  = *reinterpret_cast<const f32x4*>(&krow[idx]);
    const f32x4 np4 = *reinterpret_cast<const f32x4*>(&n_prev[(size_t)b * MM + idx]);
    const f32x4 q4  = *reinterpret_cast<const f32x4*>(&qrow[idx]);

    f32x4 n4;
    n4.x = f4.x * np4.x + i4.x * k4.x;
    n4.y = f4.y * np4.y + i4.y * k4.y;
    n4.z = f4.z * np4.z + i4.z * k4.z;
    n4.w = f4.w * np4.w + i4.w * k4.w;
    *reinterpret_cast<f32x4*>(&n_out[(size_t)b * MM + idx]) = n4;

    float part = n4.x * q4.x + n4.y * q4.y + n4.z * q4.z + n4.w * q4.w;
    #pragma unroll
    for (int off = 1; off < 64; off <<= 1) part += __shfl_xor(part, off);

    __shared__ float red[4];
    if ((tid & 63) == 0) red[tid >> 6] = part;
    __syncthreads();
    if (tid == 0) denom[b] = fmaxf(fabsf(red[0] + red[1] + red[2] + red[3]), 1.0f);
}

// ---------------------------------------------------------------------------
// Kernel 3 (dominant, HBM-bound): per (b,m) row of the matrix memory:
//   C[b,m,:] = f*c_prev[b,m,:] + (i*v)*k[b,:]          (268MB read + 268MB write)
//   ht[b,m]  = o * dot(C[b,m,:], q[b,:]) / denom[b]    (fused: no C re-read)
// One wave per row; 4 waves per block; 16B vectors everywhere; nontemporal on
// the streaming c_prev/C_out so the 1.5MB gates array stays cache-resident.
// ---------------------------------------------------------------------------
__global__ __launch_bounds__(256) void update_kernel(
    const float* __restrict__ gates, const float* __restrict__ c_prev,
    const float* __restrict__ denom,
    float* __restrict__ ht, float* __restrict__ C_out)
{
    const int tid  = threadIdx.x;
    const int wv   = tid >> 6;
    const int lane = tid & 63;
    const int row  = (blockIdx.x << 2) | wv;   // b*1024 + m
    const int b    = row >> 10;
    const int m    = row & 1023;

    const float* qrow = gates + 0 * GH + (size_t)b * HH;
    const float* krow = gates + 1 * GH + (size_t)b * HH;
    const float vt = gates[2 * GH + (size_t)b * HH + m];
    const float it = gates[3 * GH + (size_t)b * HH + m];
    const float ft = gates[4 * GH + (size_t)b * HH + m];
    const float ot = gates[5 * GH + (size_t)b * HH + m];
    const float iv = it * vt;

    const size_t base = (size_t)row << 10;
    float dot = 0.f;
    #pragma unroll
    for (int p = 0; p < 4; ++p) {
        const int idx = (p << 8) + (lane << 2);
        const f32x4 c4 = __builtin_nontemporal_load(
            reinterpret_cast<const f32x4*>(&c_prev[base + idx]));
        const f32x4 k4 = *reinterpret_cast<const f32x4*>(&krow[idx]);
        const f32x4 q4 = *reinterpret_cast<const f32x4*>(&qrow[idx]);
        f32x4 r;
        r.x = ft * c4.x + iv * k4.x;
        r.y = ft * c4.y + iv * k4.y;
        r.z = ft * c4.z + iv * k4.z;
        r.w = ft * c4.w + iv * k4.w;
        __builtin_nontemporal_store(r, reinterpret_cast<f32x4*>(&C_out[base + idx]));
        dot += r.x * q4.x + r.y * q4.y + r.z * q4.z + r.w * q4.w;
    }

    #pragma unroll
    for (int off = 1; off < 64; off <<= 1) dot += __shfl_xor(dot, off);
    if (lane == 0) ht[row] = ot * dot / denom[b];
}

// ---------------------------------------------------------------------------
extern "C" void kernel_launch(void* const* d_in, const int* in_sizes, int n_in,
                              void* d_out, int out_size, void* d_ws, size_t ws_size,
                              hipStream_t stream)
{
    const float* x      = (const float*)d_in[0];
    const float* c_prev = (const float*)d_in[1];
    const float* n_prev = (const float*)d_in[2];
    const float* Wq = (const float*)d_in[3];  const float* bq = (const float*)d_in[4];
    const float* Wk = (const float*)d_in[5];  const float* bk = (const float*)d_in[6];
    const float* Wv = (const float*)d_in[7];  const float* bv = (const float*)d_in[8];
    const float* Wi = (const float*)d_in[9];  const float* bi = (const float*)d_in[10];
    const float* Wf = (const float*)d_in[11]; const float* bf = (const float*)d_in[12];
    const float* Wo = (const float*)d_in[13]; const float* bo = (const float*)d_in[14];

    float* out   = (float*)d_out;
    float* ht    = out;                              // [64,1024]
    float* C_out = out + GH;                         // [64,1024,1024]
    float* n_out = out + GH + (size_t)BB * MM * MM;  // [64,1024]

    float* gates = (float*)d_ws;                // 6 * 65536 floats
    float* denom = gates + 6 * (size_t)GH;      // 64 floats

    gates_kernel<<<256, 512, 0, stream>>>(x, Wq, bq, Wk, bk, Wv, bv,
                                          Wi, bi, Wf, bf, Wo, bo, gates);
    n_denom_kernel<<<64, 256, 0, stream>>>(gates, n_prev, n_out, denom);
    update_kernel<<<16384, 256, 0, stream>>>(gates, c_prev, denom, ht, C_out);
}

// Round 12
// 513.819 us; speedup vs baseline: 1.0124x; 1.0124x over previous
//
#include <hip/hip_runtime.h>
#include <math.h>

#define BB 64
#define II 1024
#define HH 1024
#define MM 1024
#define GH (BB * HH)   // 65536 elements per gate plane

// Clang-native 4-float vector: required by __builtin_nontemporal_load/store
// (HIP's float4 is a HIP_vector_type class, which the builtin rejects).
typedef float f32x4 __attribute__((ext_vector_type(4)));

// ---------------------------------------------------------------------------
// Kernel 1: the six input projections.
//   gates[w][b][h], w in {0:q, 1:k(scaled), 2:v, 3:i(sig), 4:f(sig), 5:o(sig)}
// v2: x staged in LDS with COALESCED global fill (v1 read x at 4KB lane
// stride -> 64 cache lines per instruction, transaction-bound). Per k-chunk
// of 128: 512 threads fill xs[64][132] (pad 132: 16B-aligned, rotated bank
// pattern => conflict-free b128 on both write and xs[lane][kk] read).
// Weight rows remain wave-uniform broadcast loads (disjoint across blocks).
// 256 blocks x 8 waves x 3 cols = 6144 = 6*1024 columns; 33KB LDS.
// ---------------------------------------------------------------------------
__global__ __launch_bounds__(512) void gates_kernel(
    const float* __restrict__ x,
    const float* __restrict__ Wq, const float* __restrict__ bq,
    const float* __restrict__ Wk, const float* __restrict__ bk,
    const float* __restrict__ Wv, const float* __restrict__ bv,
    const float* __restrict__ Wi, const float* __restrict__ bi,
    const float* __restrict__ Wf, const float* __restrict__ bf,
    const float* __restrict__ Wo, const float* __restrict__ bo,
    float* __restrict__ gates)
{
    __shared__ float xs[64][132];

    const int tid  = threadIdx.x;
    const int lane = tid & 63;
    const int wv   = __builtin_amdgcn_readfirstlane((int)(tid >> 6));
    const int g0   = blockIdx.x * 24 + wv * 3;

    const float* wrow[3];
    float        bias[3];
    #pragma unroll
    for (int j = 0; j < 3; ++j) {
        const int g = g0 + j;
        const int s = g >> 10;        // which weight
        const int h = g & 1023;
        const float* Wb; const float* bb;
        switch (s) {
            case 0:  Wb = Wq; bb = bq; break;
            case 1:  Wb = Wk; bb = bk; break;
            case 2:  Wb = Wv; bb = bv; break;
            case 3:  Wb = Wi; bb = bi; break;
            case 4:  Wb = Wf; bb = bf; break;
            default: Wb = Wo; bb = bo; break;
        }
        wrow[j] = Wb + (size_t)h * II;
        bias[j] = bb[h];
    }

    // staging indices: thread t fills rows {t>>5, +16, +32, +48} at kk4=(t&31)*4
    const int kk4  = (tid & 31) << 2;   // 0..124
    const int brow = tid >> 5;          // 0..15

    float a0 = 0.f, a1 = 0.f, a2 = 0.f;

    for (int k0 = 0; k0 < II; k0 += 128) {
        __syncthreads();   // previous chunk fully consumed before overwrite
        #pragma unroll
        for (int pp = 0; pp < 4; ++pp) {
            const int b = brow + (pp << 4);
            const f32x4 v = *reinterpret_cast<const f32x4*>(&x[(size_t)b * II + k0 + kk4]);
            *reinterpret_cast<f32x4*>(&xs[b][kk4]) = v;
        }
        __syncthreads();

        #pragma unroll 8
        for (int kk = 0; kk < 128; kk += 4) {
            const f32x4 xv = *reinterpret_cast<const f32x4*>(&xs[lane][kk]);
            const f32x4 w0 = *reinterpret_cast<const f32x4*>(&wrow[0][k0 + kk]);
            const f32x4 w1 = *reinterpret_cast<const f32x4*>(&wrow[1][k0 + kk]);
            const f32x4 w2 = *reinterpret_cast<const f32x4*>(&wrow[2][k0 + kk]);
            a0 += xv.x * w0.x + xv.y * w0.y + xv.z * w0.z + xv.w * w0.w;
            a1 += xv.x * w1.x + xv.y * w1.y + xv.z * w1.z + xv.w * w1.w;
            a2 += xv.x * w2.x + xv.y * w2.y + xv.z * w2.z + xv.w * w2.w;
        }
    }

    float accs[3] = {a0, a1, a2};
    #pragma unroll
    for (int j = 0; j < 3; ++j) {
        const int g = g0 + j;
        const int s = g >> 10;
        const int h = g & 1023;
        float r = accs[j] + bias[j];
        if (s == 1)      r *= 0.03125f;                    // 1/sqrt(1024)
        else if (s >= 3) r = 1.0f / (1.0f + expf(-r));     // sigmoid
        gates[(size_t)s * GH + (size_t)lane * HH + h] = r;
    }
}

// ---------------------------------------------------------------------------
// Kernel 2: n = f*n_prev + i*k ; denom[b] = max(|dot(n, q)|, 1)
// One block per batch row.
// ---------------------------------------------------------------------------
__global__ __launch_bounds__(256) void n_denom_kernel(
    const float* __restrict__ gates, const float* __restrict__ n_prev,
    float* __restrict__ n_out, float* __restrict__ denom)
{
    const int b   = blockIdx.x;
    const int tid = threadIdx.x;
    const int idx = tid << 2;

    const float* qrow = gates + 0 * GH + (size_t)b * HH;
    const float* krow = gates + 1 * GH + (size_t)b * HH;
    const float* irow = gates + 3 * GH + (size_t)b * HH;
    const float* frow = gates + 4 * GH + (size_t)b * HH;

    const f32x4 f4  = *reinterpret_cast<const f32x4*>(&frow[idx]);
    const f32x4 i4  = *reinterpret_cast<const f32x4*>(&irow[idx]);
    const f32x4 k4  = *reinterpret_cast<const f32x4*>(&krow[idx]);
    const f32x4 np4 = *reinterpret_cast<const f32x4*>(&n_prev[(size_t)b * MM + idx]);
    const f32x4 q4  = *reinterpret_cast<const f32x4*>(&qrow[idx]);

    f32x4 n4;
    n4.x = f4.x * np4.x + i4.x * k4.x;
    n4.y = f4.y * np4.y + i4.y * k4.y;
    n4.z = f4.z * np4.z + i4.z * k4.z;
    n4.w = f4.w * np4.w + i4.w * k4.w;
    *reinterpret_cast<f32x4*>(&n_out[(size_t)b * MM + idx]) = n4;

    float part = n4.x * q4.x + n4.y * q4.y + n4.z * q4.z + n4.w * q4.w;
    #pragma unroll
    for (int off = 1; off < 64; off <<= 1) part += __shfl_xor(part, off);

    __shared__ float red[4];
    if ((tid & 63) == 0) red[tid >> 6] = part;
    __syncthreads();
    if (tid == 0) denom[b] = fmaxf(fabsf(red[0] + red[1] + red[2] + red[3]), 1.0f);
}

// ---------------------------------------------------------------------------
// Kernel 3 (dominant, HBM-bound): per (b,m) row of the matrix memory:
//   C[b,m,:] = f*c_prev[b,m,:] + (i*v)*k[b,:]          (268MB read + 268MB write)
//   ht[b,m]  = o * dot(C[b,m,:], q[b,:]) / denom[b]    (fused: no C re-read)
// One wave per row; 4 waves per block; 16B vectors everywhere; nontemporal on
// the streaming c_prev/C_out so the 1.5MB gates array stays cache-resident.
// ---------------------------------------------------------------------------
__global__ __launch_bounds__(256) void update_kernel(
    const float* __restrict__ gates, const float* __restrict__ c_prev,
    const float* __restrict__ denom,
    float* __restrict__ ht, float* __restrict__ C_out)
{
    const int tid  = threadIdx.x;
    const int wv   = tid >> 6;
    const int lane = tid & 63;
    const int row  = (blockIdx.x << 2) | wv;   // b*1024 + m
    const int b    = row >> 10;
    const int m    = row & 1023;

    const float* qrow = gates + 0 * GH + (size_t)b * HH;
    const float* krow = gates + 1 * GH + (size_t)b * HH;
    const float vt = gates[2 * GH + (size_t)b * HH + m];
    const float it = gates[3 * GH + (size_t)b * HH + m];
    const float ft = gates[4 * GH + (size_t)b * HH + m];
    const float ot = gates[5 * GH + (size_t)b * HH + m];
    const float iv = it * vt;

    const size_t base = (size_t)row << 10;
    float dot = 0.f;
    #pragma unroll
    for (int p = 0; p < 4; ++p) {
        const int idx = (p << 8) + (lane << 2);
        const f32x4 c4 = __builtin_nontemporal_load(
            reinterpret_cast<const f32x4*>(&c_prev[base + idx]));
        const f32x4 k4 = *reinterpret_cast<const f32x4*>(&krow[idx]);
        const f32x4 q4 = *reinterpret_cast<const f32x4*>(&qrow[idx]);
        f32x4 r;
        r.x = ft * c4.x + iv * k4.x;
        r.y = ft * c4.y + iv * k4.y;
        r.z = ft * c4.z + iv * k4.z;
        r.w = ft * c4.w + iv * k4.w;
        __builtin_nontemporal_store(r, reinterpret_cast<f32x4*>(&C_out[base + idx]));
        dot += r.x * q4.x + r.y * q4.y + r.z * q4.z + r.w * q4.w;
    }

    #pragma unroll
    for (int off = 1; off < 64; off <<= 1) dot += __shfl_xor(dot, off);
    if (lane == 0) ht[row] = ot * dot / denom[b];
}

// ---------------------------------------------------------------------------
extern "C" void kernel_launch(void* const* d_in, const int* in_sizes, int n_in,
                              void* d_out, int out_size, void* d_ws, size_t ws_size,
                              hipStream_t stream)
{
    const float* x      = (const float*)d_in[0];
    const float* c_prev = (const float*)d_in[1];
    const float* n_prev = (const float*)d_in[2];
    const float* Wq = (const float*)d_in[3];  const float* bq = (const float*)d_in[4];
    const float* Wk = (const float*)d_in[5];  const float* bk = (const float*)d_in[6];
    const float* Wv = (const float*)d_in[7];  const float* bv = (const float*)d_in[8];
    const float* Wi = (const float*)d_in[9];  const float* bi = (const float*)d_in[10];
    const float* Wf = (const float*)d_in[11]; const float* bf = (const float*)d_in[12];
    const float* Wo = (const float*)d_in[13]; const float* bo = (const float*)d_in[14];

    float* out   = (float*)d_out;
    float* ht    = out;                              // [64,1024]
    float* C_out = out + GH;                         // [64,1024,1024]
    float* n_out = out + GH + (size_t)BB * MM * MM;  // [64,1024]

    float* gates = (float*)d_ws;                // 6 * 65536 floats
    float* denom = gates + 6 * (size_t)GH;      // 64 floats

    gates_kernel<<<256, 512, 0, stream>>>(x, Wq, bq, Wk, bk, Wv, bv,
                                          Wi, bi, Wf, bf, Wo, bo, gates);
    n_denom_kernel<<<64, 256, 0, stream>>>(gates, n_prev, n_out, denom);
    update_kernel<<<16384, 256, 0, stream>>>(gates, c_prev, denom, ht, C_out);
}